// Round 6
// baseline (214.311 us; speedup 1.0000x reference)
//
#include <hip/hip_runtime.h>
#include <stdint.h>

#define B_SZ 2
#define T_SZ 2048
#define C_SZ 1024
#define NH   16
#define NKV  4
#define HD   64
#define KVD  256
#define QKV_N 1536

typedef __attribute__((ext_vector_type(8))) short bf16x8;
typedef __attribute__((ext_vector_type(4))) float f32x4;

#define GL(p) ((const __attribute__((address_space(1))) void*)(p))
#define LD(p) ((__attribute__((address_space(3))) void*)(p))

__device__ inline unsigned short f2bf(float f) {
  union { float f; unsigned u; } v; v.f = f;
  unsigned u = v.u;
  unsigned r = (u + 0x7fffu + ((u >> 16) & 1u)) >> 16;
  return (unsigned short)r;
}
__device__ inline unsigned short bftrunc(float f) {  // truncate: 1 inst; bias cancels in O/l
  union { float f; unsigned u; } v; v.f = f;
  return (unsigned short)(v.u >> 16);
}

// ---------------- fused fp32->bf16 convert (5 segments) + gate precompute, 1 launch ----------------
struct CvtArgs {
  const float *s0, *s1, *s2, *s3, *s4;
  unsigned short *d0, *d1, *d2, *d3, *d4;
  const float *x, *Wg;
  float *gate;           // [B*T][NKV]
};
__global__ __launch_bounds__(256) void cvt_all(CvtArgs a) {
  int blk = blockIdx.x, tid = threadIdx.x;
  if (blk >= 6656) {  // gate: 3*sigmoid(x[:, :12] @ Wg^T)
    int idx = (blk - 6656) * 256 + tid;
    int bt = idx >> 2, kh = idx & 3;
    float s = 0.f;
#pragma unroll
    for (int j = 0; j < 12; j++) s += a.x[(size_t)bt * C_SZ + j] * a.Wg[kh * 12 + j];
    a.gate[idx] = 3.f / (1.f + __expf(-s));
    return;
  }
  const float* s; unsigned short* d; int i;
  if      (blk < 4096) { s = a.s0; d = a.d0; i = blk * 256 + tid; }
  else if (blk < 5120) { s = a.s1; d = a.d1; i = (blk - 4096) * 256 + tid; }
  else if (blk < 5376) { s = a.s2; d = a.d2; i = (blk - 5120) * 256 + tid; }
  else if (blk < 5632) { s = a.s3; d = a.d3; i = (blk - 5376) * 256 + tid; }
  else                 { s = a.s4; d = a.d4; i = (blk - 5632) * 256 + tid; }
  float4 f = ((const float4*)s)[i];
  ushort4 o;
  o.x = f2bf(f.x); o.y = f2bf(f.y); o.z = f2bf(f.z); o.w = f2bf(f.w);
  ((ushort4*)d)[i] = o;
}

// ================= GEMM core: m97-exact 128x128 tile, BK=64 as two 32-panels =================
#define GEMM_PROLOG(A, Bm, K)                                                        \
  __shared__ unsigned short As[2][128 * 32];                                         \
  __shared__ unsigned short Bs[2][128 * 32];                                         \
  int tid  = threadIdx.x;                                                            \
  int lane = tid & 63;                                                               \
  int wave = tid >> 6;                                                               \
  int quad = lane >> 4;                                                              \
  int l16  = lane & 15;                                                              \
  int m0 = blockIdx.y * 128;                                                         \
  int n0 = blockIdx.x * 128;                                                         \
  int wm = (wave & 1) * 64;                                                          \
  int wn = (wave >> 1) * 64;                                                         \
  f32x4 acc[4][4];                                                                   \
  _Pragma("unroll") for (int i = 0; i < 4; i++)                                      \
    _Pragma("unroll") for (int j = 0; j < 4; j++)                                    \
      acc[i][j] = (f32x4){0.f, 0.f, 0.f, 0.f};                                       \
  int lrow = lane >> 2;                                                              \
  int lcol = (lane & 3) * 8;                                                         \
  int srow = wave * 32;                                                              \
  const unsigned short* aP = &A[(size_t)(m0 + srow + lrow) * K + lcol];              \
  const unsigned short* bP = &Bm[(size_t)(n0 + srow + lrow) * K + lcol];             \
  for (int k0 = 0; k0 < K; k0 += 64) {                                               \
    __syncthreads();                                                                 \
    _Pragma("unroll") for (int p = 0; p < 2; p++) {                                  \
      __builtin_amdgcn_global_load_lds(GL(aP + k0 + p * 32),          LD(&As[p][srow * 32]),        16, 0, 0); \
      __builtin_amdgcn_global_load_lds(GL(aP + 16 * (size_t)K + k0 + p * 32), LD(&As[p][(srow + 16) * 32]), 16, 0, 0); \
      __builtin_amdgcn_global_load_lds(GL(bP + k0 + p * 32),          LD(&Bs[p][srow * 32]),        16, 0, 0); \
      __builtin_amdgcn_global_load_lds(GL(bP + 16 * (size_t)K + k0 + p * 32), LD(&Bs[p][(srow + 16) * 32]), 16, 0, 0); \
    }                                                                                \
    __syncthreads();                                                                 \
    _Pragma("unroll") for (int p = 0; p < 2; p++) {                                  \
      bf16x8 af[4], bfr[4];                                                          \
      _Pragma("unroll") for (int i = 0; i < 4; i++)                                  \
        af[i] = *(const bf16x8*)&As[p][(wm + i * 16 + l16) * 32 + quad * 8];         \
      _Pragma("unroll") for (int j = 0; j < 4; j++)                                  \
        bfr[j] = *(const bf16x8*)&Bs[p][(wn + j * 16 + l16) * 32 + quad * 8];        \
      _Pragma("unroll") for (int i = 0; i < 4; i++)                                  \
        _Pragma("unroll") for (int j = 0; j < 4; j++)                                \
          acc[i][j] = __builtin_amdgcn_mfma_f32_16x16x32_bf16(af[i], bfr[j], acc[i][j], 0, 0, 0); \
    }                                                                                \
  }

// ---------------- gemm2: C[m,n] = sum_k A[m,k]*B[n,k], fp32 out ----------------
__global__ __launch_bounds__(256) void gemm_bt(const unsigned short* __restrict__ A,
                                               const unsigned short* __restrict__ Bm,
                                               float* __restrict__ C,
                                               int N, int K) {
  GEMM_PROLOG(A, Bm, K)
#pragma unroll
  for (int i = 0; i < 4; i++) {
#pragma unroll
    for (int j = 0; j < 4; j++) {
      int col = n0 + wn + j * 16 + l16;
#pragma unroll
      for (int r = 0; r < 4; r++) {
        int row = m0 + wm + i * 16 + quad * 4 + r;
        C[(size_t)row * N + col] = acc[i][j][r];
      }
    }
  }
}

// ---------------- gemm1 fused: qkv proj + RoPE + RMSNorm + gate*ve, bf16 out ----------------
// Wave's 64 cols = exactly one head (wn multiple of 64). RoPE partners acc[i][j]/acc[i][j+2]
// are in the same lane. q scale folds 1.2*(1/8)*log2(e) (attention uses exp2); k scale 1.2.
// vt written transposed (B,NKV,HD,T) for the PV B-operand.
__global__ __launch_bounds__(256) void gemm_qkv(const unsigned short* __restrict__ A,
                                                const unsigned short* __restrict__ Bm,
                                                const float* __restrict__ ve,
                                                const float* __restrict__ cosb,
                                                const float* __restrict__ sinb,
                                                const float* __restrict__ gateArr,
                                                unsigned short* __restrict__ qa,
                                                unsigned short* __restrict__ ka,
                                                unsigned short* __restrict__ vt) {
  const int K = C_SZ;
  GEMM_PROLOG(A, Bm, K)

  int colbase = n0 + wn;   // multiple of 64
  if (colbase < 1280) {    // Q or K head
    int isQ = colbase < 1024;
    int h   = isQ ? (colbase >> 6) : ((colbase - 1024) >> 6);
    float scale = isQ ? (0.15f * 1.44269504088896f) : 1.2f;
    unsigned short* dst = isQ ? qa : ka;
    int nheads = isQ ? NH : NKV;
#pragma unroll
    for (int i = 0; i < 4; i++) {
#pragma unroll
      for (int r = 0; r < 4; r++) {
        int row = m0 + wm + i * 16 + quad * 4 + r;   // bt
        int t = row & (T_SZ - 1), b = row >> 11;
        float a10 = acc[i][0][r], a11 = acc[i][1][r];
        float a20 = acc[i][2][r], a21 = acc[i][3][r];
        float cv0 = cosb[t * 32 + l16],      sv0 = sinb[t * 32 + l16];
        float cv1 = cosb[t * 32 + 16 + l16], sv1 = sinb[t * 32 + 16 + l16];
        float o10 =  a10 * cv0 + a20 * sv0;
        float o11 =  a11 * cv1 + a21 * sv1;
        float o20 = -a10 * sv0 + a20 * cv0;
        float o21 = -a11 * sv1 + a21 * cv1;
        float ssq = o10 * o10 + o11 * o11 + o20 * o20 + o21 * o21;
        ssq += __shfl_xor(ssq, 1);
        ssq += __shfl_xor(ssq, 2);
        ssq += __shfl_xor(ssq, 4);
        ssq += __shfl_xor(ssq, 8);
        float rn = rsqrtf(ssq * (1.f / 64.f) + 1e-6f) * scale;
        size_t base = ((size_t)(b * nheads + h) * T_SZ + t) * HD;
        dst[base + l16]      = f2bf(o10 * rn);
        dst[base + 16 + l16] = f2bf(o11 * rn);
        dst[base + 32 + l16] = f2bf(o20 * rn);
        dst[base + 48 + l16] = f2bf(o21 * rn);
      }
    }
  } else {                 // V head: add gate*ve, write transposed
    int kh = (colbase - 1280) >> 6;
#pragma unroll
    for (int i = 0; i < 4; i++) {
#pragma unroll
      for (int r = 0; r < 4; r++) {
        int row = m0 + wm + i * 16 + quad * 4 + r;   // bt
        int t = row & (T_SZ - 1), b = row >> 11;
        float g = gateArr[row * 4 + kh];
        size_t vbase = ((size_t)(b * NKV + kh) * HD) * T_SZ;
#pragma unroll
        for (int j = 0; j < 4; j++) {
          int d = j * 16 + l16;
          float val = acc[i][j][r] + g * ve[(size_t)row * KVD + kh * HD + d];
          vt[vbase + (size_t)d * T_SZ + t] = f2bf(val);
        }
      }
    }
  }
}

// ---------------- causal flash attention: Q-tile=128, K-tile=128, exp2, no reductions ----------------
// |q|,|k| fixed by RMSNorm -> scores bounded -> no max-subtraction. P=exp2(S) (log2e in q).
// Row-sum l via ones-MFMA. P truncated bf16 (bias cancels in O/l). K-tile=128 halves barriers;
// K/V prefetch issued AFTER the consume barrier so loads fly during the whole compute phase.
#define KST 72    // K rows: 64 cols + pad (2-way bank aliasing = free)
#define VST 136   // V/P rows: 128 cols + pad (2-way)
__global__ __launch_bounds__(256) void attn(const unsigned short* __restrict__ qa,
                                            const unsigned short* __restrict__ ka,
                                            const unsigned short* __restrict__ vt,
                                            unsigned short* __restrict__ y) {
  // pair qt with 15-qt so co-resident blocks sum to equal work
  int bid = blockIdx.x;
  int half = bid >> 8, r = bid & 255;
  int qt = half ? (r & 15) : 15 - (r & 15);
  int bh = (half << 4) | (r >> 4);
  int b = bh >> 4, h = bh & 15;
  int kh = h >> 2;
  int tid = threadIdx.x;
  int wave = tid >> 6, lane = tid & 63;
  int quad = lane >> 4, l16 = lane & 15;

  __shared__ unsigned short Ks[128 * KST];   // [t_local][d]
  __shared__ unsigned short Vs[64 * VST];    // [d][t_local]
  __shared__ unsigned short Ps[128 * VST];   // [q_row][t_local]
  unsigned short* Pw = &Ps[(wave * 32) * VST];

  bf16x8 aq[2][2];
#pragma unroll
  for (int mi = 0; mi < 2; mi++) {
    int tq = qt * 128 + wave * 32 + mi * 16 + l16;
    const unsigned short* qp = &qa[((size_t)(b * NH + h) * T_SZ + tq) * HD];
    aq[mi][0] = *(const bf16x8*)&qp[quad * 8];
    aq[mi][1] = *(const bf16x8*)&qp[32 + quad * 8];
  }

  const unsigned short one_bf = 0x3F80;
  bf16x8 vones = {(short)one_bf, (short)one_bf, (short)one_bf, (short)one_bf,
                  (short)one_bf, (short)one_bf, (short)one_bf, (short)one_bf};

  f32x4 oacc[2][4];
  f32x4 lacc[2];
#pragma unroll
  for (int mi = 0; mi < 2; mi++) {
    lacc[mi] = (f32x4){0.f, 0.f, 0.f, 0.f};
#pragma unroll
    for (int d = 0; d < 4; d++) oacc[mi][d] = (f32x4){0.f, 0.f, 0.f, 0.f};
  }

  // staging indices: K 128x64 (4 uint4/thread), V 64x128 (4 uint4/thread)
  int klr = tid >> 1, klc = (tid & 1) * 32;
  int vlr = tid >> 2, vlc = (tid & 3) * 32;

  const unsigned short* kbase = &ka[(size_t)(b * NKV + kh) * T_SZ * HD];
  const unsigned short* vbase = &vt[(size_t)(b * NKV + kh) * HD * T_SZ];

  int nj = qt + 1;

  uint4 kr[4], vr[4];
  {
    const unsigned short* kp = &kbase[(size_t)klr * HD + klc];
    const unsigned short* vp = &vbase[(size_t)vlr * T_SZ + vlc];
#pragma unroll
    for (int q = 0; q < 4; q++) { kr[q] = *(const uint4*)(kp + q * 8); vr[q] = *(const uint4*)(vp + q * 8); }
  }

  int qrow0 = qt * 128 + wave * 32;

  for (int j = 0; j < nj; j++) {
    __syncthreads();
#pragma unroll
    for (int q = 0; q < 4; q++) {
      *(uint4*)&Ks[klr * KST + klc + q * 8] = kr[q];
      *(uint4*)&Vs[vlr * VST + vlc + q * 8] = vr[q];
    }
    __syncthreads();

    if (j + 1 < nj) {  // issue next tile's loads now; they fly during this tile's compute
      const unsigned short* kp = &kbase[(size_t)((j + 1) * 128 + klr) * HD + klc];
      const unsigned short* vp = &vbase[(size_t)vlr * T_SZ + (j + 1) * 128 + vlc];
#pragma unroll
      for (int q = 0; q < 4; q++) { kr[q] = *(const uint4*)(kp + q * 8); vr[q] = *(const uint4*)(vp + q * 8); }
    }

    // S' = Q K^T over 128 cols (8 n-blocks); K-frags shared across both m-blocks
    f32x4 sa[2][8];
#pragma unroll
    for (int nb = 0; nb < 8; nb++) {
      bf16x8 bk0 = *(const bf16x8*)&Ks[(nb * 16 + l16) * KST + quad * 8];
      bf16x8 bk1 = *(const bf16x8*)&Ks[(nb * 16 + l16) * KST + 32 + quad * 8];
#pragma unroll
      for (int mi = 0; mi < 2; mi++) {
        f32x4 s = (f32x4){0.f, 0.f, 0.f, 0.f};
        s = __builtin_amdgcn_mfma_f32_16x16x32_bf16(aq[mi][0], bk0, s, 0, 0, 0);
        s = __builtin_amdgcn_mfma_f32_16x16x32_bf16(aq[mi][1], bk1, s, 0, 0, 0);
        sa[mi][nb] = s;
      }
    }

    // causal mask: only the diagonal tile (j == qt) is partial
    if (j == qt) {
#pragma unroll
      for (int mi = 0; mi < 2; mi++) {
        int rowLow = qrow0 + mi * 16;
#pragma unroll
        for (int nb = 0; nb < 8; nb++) {
          int col = j * 128 + nb * 16 + l16;
#pragma unroll
          for (int i = 0; i < 4; i++) {
            if (col > rowLow + quad * 4 + i) sa[mi][nb][i] = -__builtin_inff();
          }
        }
      }
    }

    // P = exp2(S') -> truncated bf16 -> LDS (C-layout -> A-layout, same-wave region)
#pragma unroll
    for (int mi = 0; mi < 2; mi++)
#pragma unroll
      for (int nb = 0; nb < 8; nb++)
#pragma unroll
        for (int i = 0; i < 4; i++)
          Pw[(mi * 16 + quad * 4 + i) * VST + nb * 16 + l16] =
              bftrunc(__builtin_amdgcn_exp2f(sa[mi][nb][i]));

    bf16x8 ap[2][4];
#pragma unroll
    for (int mi = 0; mi < 2; mi++) {
#pragma unroll
      for (int c = 0; c < 4; c++) {
        ap[mi][c] = *(const bf16x8*)&Pw[(mi * 16 + l16) * VST + c * 32 + quad * 8];
        lacc[mi] = __builtin_amdgcn_mfma_f32_16x16x32_bf16(ap[mi][c], vones, lacc[mi], 0, 0, 0);
      }
    }
#pragma unroll
    for (int c = 0; c < 4; c++) {
#pragma unroll
      for (int d = 0; d < 4; d++) {
        bf16x8 bv = *(const bf16x8*)&Vs[(d * 16 + l16) * VST + c * 32 + quad * 8];
#pragma unroll
        for (int mi = 0; mi < 2; mi++)
          oacc[mi][d] = __builtin_amdgcn_mfma_f32_16x16x32_bf16(ap[mi][c], bv, oacc[mi][d], 0, 0, 0);
      }
    }
  }

#pragma unroll
  for (int mi = 0; mi < 2; mi++) {
#pragma unroll
    for (int i = 0; i < 4; i++) {
      int tq = qrow0 + mi * 16 + quad * 4 + i;
      float inv = 1.f / lacc[mi][i];
#pragma unroll
      for (int d = 0; d < 4; d++) {
        y[((size_t)(b * T_SZ) + tq) * C_SZ + h * HD + d * 16 + l16] = f2bf(oacc[mi][d][i] * inv);
      }
    }
  }
}

extern "C" void kernel_launch(void* const* d_in, const int* in_sizes, int n_in,
                              void* d_out, int out_size, void* d_ws, size_t ws_size,
                              hipStream_t stream) {
  const float* x    = (const float*)d_in[0];
  const float* ve   = (const float*)d_in[1];
  const float* cosb = (const float*)d_in[2];
  const float* sinb = (const float*)d_in[3];
  const float* Wq   = (const float*)d_in[4];
  const float* Wk   = (const float*)d_in[5];
  const float* Wv   = (const float*)d_in[6];
  const float* Wo   = (const float*)d_in[7];
  const float* Wg   = (const float*)d_in[8];
  float* out = (float*)d_out;

  const size_t MB = 1024 * 1024;
  char* ws = (char*)d_ws;
  unsigned short* xb    = (unsigned short*)(ws);             // 8 MB (reused as yb)
  unsigned short* wqkvb = (unsigned short*)(ws + 8 * MB);    // 3 MB
  unsigned short* wob   = (unsigned short*)(ws + 11 * MB);   // 2 MB
  unsigned short* qab   = (unsigned short*)(ws + 13 * MB);   // 8 MB
  unsigned short* kab   = (unsigned short*)(ws + 21 * MB);   // 2 MB
  unsigned short* vtb   = (unsigned short*)(ws + 23 * MB);   // 2 MB
  float*          gateA = (float*)(ws + 25 * MB);            // 64 KB
  unsigned short* yb    = xb;                                // reuse after gemm_qkv

  CvtArgs ca;
  ca.s0 = x;  ca.d0 = xb;
  ca.s1 = Wq; ca.d1 = wqkvb;
  ca.s2 = Wk; ca.d2 = wqkvb + 1024 * 1024;
  ca.s3 = Wv; ca.d3 = wqkvb + 1280 * 1024;
  ca.s4 = Wo; ca.d4 = wob;
  ca.x = x; ca.Wg = Wg; ca.gate = gateA;
  cvt_all<<<6720, 256, 0, stream>>>(ca);

  gemm_qkv<<<dim3(QKV_N / 128, (B_SZ * T_SZ) / 128), 256, 0, stream>>>(
      xb, wqkvb, ve, cosb, sinb, gateA, qab, kab, vtb);

  attn<<<512, 256, 0, stream>>>(qab, kab, vtb, yb);

  gemm_bt<<<dim3(C_SZ / 128, (B_SZ * T_SZ) / 128), 256, 0, stream>>>(
      yb, wob, out, C_SZ, C_SZ);
}

// Round 7
// 172.000 us; speedup vs baseline: 1.2460x; 1.2460x over previous
//
#include <hip/hip_runtime.h>
#include <stdint.h>

#define B_SZ 2
#define T_SZ 2048
#define C_SZ 1024
#define NH   16
#define NKV  4
#define HD   64
#define KVD  256
#define QKV_N 1536

typedef __attribute__((ext_vector_type(8))) short bf16x8;
typedef __attribute__((ext_vector_type(4))) float f32x4;

#define GL(p) ((const __attribute__((address_space(1))) void*)(p))
#define LD(p) ((__attribute__((address_space(3))) void*)(p))

__device__ inline unsigned short f2bf(float f) {
  union { float f; unsigned u; } v; v.f = f;
  unsigned u = v.u;
  unsigned r = (u + 0x7fffu + ((u >> 16) & 1u)) >> 16;
  return (unsigned short)r;
}
__device__ inline unsigned short bftrunc(float f) {  // truncate: 1 inst; bias cancels in O/l
  union { float f; unsigned u; } v; v.f = f;
  return (unsigned short)(v.u >> 16);
}

// ---------------- fused fp32->bf16 convert (5 segments) + gate precompute, 1 launch ----------------
struct CvtArgs {
  const float *s0, *s1, *s2, *s3, *s4;
  unsigned short *d0, *d1, *d2, *d3, *d4;
  const float *x, *Wg;
  float *gate;           // [B*T][NKV]
};
__global__ __launch_bounds__(256) void cvt_all(CvtArgs a) {
  int blk = blockIdx.x, tid = threadIdx.x;
  if (blk >= 6656) {  // gate: 3*sigmoid(x[:, :12] @ Wg^T)
    int idx = (blk - 6656) * 256 + tid;
    int bt = idx >> 2, kh = idx & 3;
    float s = 0.f;
#pragma unroll
    for (int j = 0; j < 12; j++) s += a.x[(size_t)bt * C_SZ + j] * a.Wg[kh * 12 + j];
    a.gate[idx] = 3.f / (1.f + __expf(-s));
    return;
  }
  const float* s; unsigned short* d; int i;
  if      (blk < 4096) { s = a.s0; d = a.d0; i = blk * 256 + tid; }
  else if (blk < 5120) { s = a.s1; d = a.d1; i = (blk - 4096) * 256 + tid; }
  else if (blk < 5376) { s = a.s2; d = a.d2; i = (blk - 5120) * 256 + tid; }
  else if (blk < 5632) { s = a.s3; d = a.d3; i = (blk - 5376) * 256 + tid; }
  else                 { s = a.s4; d = a.d4; i = (blk - 5632) * 256 + tid; }
  float4 f = ((const float4*)s)[i];
  ushort4 o;
  o.x = f2bf(f.x); o.y = f2bf(f.y); o.z = f2bf(f.z); o.w = f2bf(f.w);
  ((ushort4*)d)[i] = o;
}

// ========== GEMM core: BM=64 x BN=128 (round-5 winner), BK=128 as four 32-panels ==========
// LDS 48 KB -> still 3 blocks/CU (144 <= 160 KB); 8 barrier pairs instead of 16.
#define GEMM_PROLOG(A, Bm, K)                                                        \
  __shared__ unsigned short As[4][64 * 32];                                          \
  __shared__ unsigned short Bs[4][128 * 32];                                         \
  int tid  = threadIdx.x;                                                            \
  int lane = tid & 63;                                                               \
  int wave = tid >> 6;                                                               \
  int quad = lane >> 4;                                                              \
  int l16  = lane & 15;                                                              \
  int m0 = blockIdx.y * 64;                                                          \
  int n0 = blockIdx.x * 128;                                                         \
  int wm = (wave & 1) * 32;                                                          \
  int wn = (wave >> 1) * 64;                                                         \
  f32x4 acc[2][4];                                                                   \
  _Pragma("unroll") for (int i = 0; i < 2; i++)                                      \
    _Pragma("unroll") for (int j = 0; j < 4; j++)                                    \
      acc[i][j] = (f32x4){0.f, 0.f, 0.f, 0.f};                                       \
  int lrow = lane >> 2;                                                              \
  int lcol = (lane & 3) * 8;                                                         \
  int srowA = wave * 16;                                                             \
  int srowB = wave * 32;                                                             \
  const unsigned short* aP  = &A[(size_t)(m0 + srowA + lrow) * K + lcol];            \
  const unsigned short* b0P = &Bm[(size_t)(n0 + srowB + lrow) * K + lcol];           \
  const unsigned short* b1P = b0P + 16 * (size_t)K;                                  \
  for (int k0 = 0; k0 < K; k0 += 128) {                                              \
    __syncthreads();                                                                 \
    _Pragma("unroll") for (int p = 0; p < 4; p++) {                                  \
      __builtin_amdgcn_global_load_lds(GL(aP  + k0 + p * 32), LD(&As[p][srowA * 32]),        16, 0, 0); \
      __builtin_amdgcn_global_load_lds(GL(b0P + k0 + p * 32), LD(&Bs[p][srowB * 32]),        16, 0, 0); \
      __builtin_amdgcn_global_load_lds(GL(b1P + k0 + p * 32), LD(&Bs[p][(srowB + 16) * 32]), 16, 0, 0); \
    }                                                                                \
    __syncthreads();                                                                 \
    _Pragma("unroll") for (int p = 0; p < 4; p++) {                                  \
      bf16x8 af[2], bfr[4];                                                          \
      _Pragma("unroll") for (int i = 0; i < 2; i++)                                  \
        af[i] = *(const bf16x8*)&As[p][(wm + i * 16 + l16) * 32 + quad * 8];         \
      _Pragma("unroll") for (int j = 0; j < 4; j++)                                  \
        bfr[j] = *(const bf16x8*)&Bs[p][(wn + j * 16 + l16) * 32 + quad * 8];        \
      _Pragma("unroll") for (int i = 0; i < 2; i++)                                  \
        _Pragma("unroll") for (int j = 0; j < 4; j++)                                \
          acc[i][j] = __builtin_amdgcn_mfma_f32_16x16x32_bf16(af[i], bfr[j], acc[i][j], 0, 0, 0); \
    }                                                                                \
  }

// ---------------- gemm2: C[m,n] = sum_k A[m,k]*B[n,k], fp32 out ----------------
__global__ __launch_bounds__(256) void gemm_bt(const unsigned short* __restrict__ A,
                                               const unsigned short* __restrict__ Bm,
                                               float* __restrict__ C,
                                               int N, int K) {
  GEMM_PROLOG(A, Bm, K)
#pragma unroll
  for (int i = 0; i < 2; i++) {
#pragma unroll
    for (int j = 0; j < 4; j++) {
      int col = n0 + wn + j * 16 + l16;
#pragma unroll
      for (int r = 0; r < 4; r++) {
        int row = m0 + wm + i * 16 + quad * 4 + r;
        C[(size_t)row * N + col] = acc[i][j][r];
      }
    }
  }
}

// ---------------- gemm1 fused: qkv proj + RoPE + RMSNorm + gate*ve, bf16 out ----------------
// Wave's 64 cols = one head. RoPE partners acc[i][j]/acc[i][j+2] same lane.
// q scale folds 1.2*(1/8)*log2(e) (attention uses exp2); k scale 1.2.
// vt written transposed (B,NKV,HD,T).
__global__ __launch_bounds__(256) void gemm_qkv(const unsigned short* __restrict__ A,
                                                const unsigned short* __restrict__ Bm,
                                                const float* __restrict__ ve,
                                                const float* __restrict__ cosb,
                                                const float* __restrict__ sinb,
                                                const float* __restrict__ gateArr,
                                                unsigned short* __restrict__ qa,
                                                unsigned short* __restrict__ ka,
                                                unsigned short* __restrict__ vt) {
  const int K = C_SZ;
  GEMM_PROLOG(A, Bm, K)

  int colbase = n0 + wn;   // multiple of 64
  if (colbase < 1280) {    // Q or K head
    int isQ = colbase < 1024;
    int h   = isQ ? (colbase >> 6) : ((colbase - 1024) >> 6);
    float scale = isQ ? (0.15f * 1.44269504088896f) : 1.2f;
    unsigned short* dst = isQ ? qa : ka;
    int nheads = isQ ? NH : NKV;
#pragma unroll
    for (int i = 0; i < 2; i++) {
#pragma unroll
      for (int r = 0; r < 4; r++) {
        int row = m0 + wm + i * 16 + quad * 4 + r;   // bt
        int t = row & (T_SZ - 1), b = row >> 11;
        float a10 = acc[i][0][r], a11 = acc[i][1][r];
        float a20 = acc[i][2][r], a21 = acc[i][3][r];
        float cv0 = cosb[t * 32 + l16],      sv0 = sinb[t * 32 + l16];
        float cv1 = cosb[t * 32 + 16 + l16], sv1 = sinb[t * 32 + 16 + l16];
        float o10 =  a10 * cv0 + a20 * sv0;
        float o11 =  a11 * cv1 + a21 * sv1;
        float o20 = -a10 * sv0 + a20 * cv0;
        float o21 = -a11 * sv1 + a21 * cv1;
        float ssq = o10 * o10 + o11 * o11 + o20 * o20 + o21 * o21;
        ssq += __shfl_xor(ssq, 1);
        ssq += __shfl_xor(ssq, 2);
        ssq += __shfl_xor(ssq, 4);
        ssq += __shfl_xor(ssq, 8);
        float rn = rsqrtf(ssq * (1.f / 64.f) + 1e-6f) * scale;
        size_t base = ((size_t)(b * nheads + h) * T_SZ + t) * HD;
        dst[base + l16]      = f2bf(o10 * rn);
        dst[base + 16 + l16] = f2bf(o11 * rn);
        dst[base + 32 + l16] = f2bf(o20 * rn);
        dst[base + 48 + l16] = f2bf(o21 * rn);
      }
    }
  } else {                 // V head: add gate*ve, write transposed
    int kh = (colbase - 1280) >> 6;
#pragma unroll
    for (int i = 0; i < 2; i++) {
#pragma unroll
      for (int r = 0; r < 4; r++) {
        int row = m0 + wm + i * 16 + quad * 4 + r;   // bt
        int t = row & (T_SZ - 1), b = row >> 11;
        float g = gateArr[row * 4 + kh];
        size_t vbase = ((size_t)(b * NKV + kh) * HD) * T_SZ;
#pragma unroll
        for (int j = 0; j < 4; j++) {
          int d = j * 16 + l16;
          float val = acc[i][j][r] + g * ve[(size_t)row * KVD + kh * HD + d];
          vt[vbase + (size_t)d * T_SZ + t] = f2bf(val);
        }
      }
    }
  }
}

// ---------------- causal flash attention: Q-tile=128, K-tile=64, S^T trick ----------------
// Computes S^T = K·Q^T (operand swap, zero cost): C-layout then gives each lane 4
// consecutive-t values at fixed q, so P goes to LDS as 8 ds_write_b64 (not 32 b16),
// already in [q][t] A-operand layout. exp2 (log2e folded in q), row-sum via ones-MFMA,
// no max-subtraction (|q|,|k| fixed by RMSNorm -> scores bounded). Prefetch issued
// AFTER the consume barrier so global loads fly through the whole compute phase.
#define KST 72
#define PST 72
__global__ __launch_bounds__(256) void attn(const unsigned short* __restrict__ qa,
                                            const unsigned short* __restrict__ ka,
                                            const unsigned short* __restrict__ vt,
                                            unsigned short* __restrict__ y) {
  // pair qt with 15-qt so co-resident blocks sum to equal work
  int bid = blockIdx.x;
  int half = bid >> 8, r = bid & 255;
  int qt = half ? (r & 15) : 15 - (r & 15);
  int bh = (half << 4) | (r >> 4);
  int b = bh >> 4, h = bh & 15;
  int kh = h >> 2;
  int tid = threadIdx.x;
  int wave = tid >> 6, lane = tid & 63;
  int quad = lane >> 4, l16 = lane & 15;

  __shared__ unsigned short Ks[64 * KST];    // [t_local][d]
  __shared__ unsigned short Vs[64 * KST];    // [d][t_local]
  __shared__ unsigned short Ps[128 * PST];   // [q_local][t_local]
  unsigned short* Pw = &Ps[(wave * 32) * PST];

  // Q fragments (B operand): lane l16 = q within block, quad*8+j = d
  bf16x8 bq[2][2];
#pragma unroll
  for (int qi = 0; qi < 2; qi++) {
    int tq = qt * 128 + wave * 32 + qi * 16 + l16;
    const unsigned short* qp = &qa[((size_t)(b * NH + h) * T_SZ + tq) * HD];
    bq[qi][0] = *(const bf16x8*)&qp[quad * 8];
    bq[qi][1] = *(const bf16x8*)&qp[32 + quad * 8];
  }

  const unsigned short one_bf = 0x3F80;
  bf16x8 vones = {(short)one_bf, (short)one_bf, (short)one_bf, (short)one_bf,
                  (short)one_bf, (short)one_bf, (short)one_bf, (short)one_bf};

  f32x4 oacc[2][4];
  f32x4 lacc[2];
#pragma unroll
  for (int qi = 0; qi < 2; qi++) {
    lacc[qi] = (f32x4){0.f, 0.f, 0.f, 0.f};
#pragma unroll
    for (int d = 0; d < 4; d++) oacc[qi][d] = (f32x4){0.f, 0.f, 0.f, 0.f};
  }

  int lr = tid >> 2;          // 0..63
  int lc = (tid & 3) * 16;    // 0,16,32,48

  const unsigned short* kbase = &ka[(size_t)(b * NKV + kh) * T_SZ * HD];
  const unsigned short* vbase = &vt[(size_t)(b * NKV + kh) * HD * T_SZ];

  int nj = 2 * qt + 2;

  uint4 k0, k1, v0, v1;
  {
    const unsigned short* kp = &kbase[(size_t)lr * HD + lc];
    const unsigned short* vp = &vbase[(size_t)lr * T_SZ + lc];
    k0 = *(const uint4*)(kp);
    k1 = *(const uint4*)(kp + 8);
    v0 = *(const uint4*)(vp);
    v1 = *(const uint4*)(vp + 8);
  }

  int qrow0 = qt * 128 + wave * 32;

  for (int j = 0; j < nj; j++) {
    __syncthreads();
    *(uint4*)&Ks[lr * KST + lc]     = k0;
    *(uint4*)&Ks[lr * KST + lc + 8] = k1;
    *(uint4*)&Vs[lr * KST + lc]     = v0;
    *(uint4*)&Vs[lr * KST + lc + 8] = v1;
    __syncthreads();

    if (j + 1 < nj) {  // issue next tile's loads now; they fly through this tile's compute
      const unsigned short* kp = &kbase[(size_t)((j + 1) * 64 + lr) * HD + lc];
      const unsigned short* vp = &vbase[(size_t)lr * T_SZ + (j + 1) * 64 + lc];
      k0 = *(const uint4*)(kp);
      k1 = *(const uint4*)(kp + 8);
      v0 = *(const uint4*)(vp);
      v1 = *(const uint4*)(vp + 8);
    }

    // S^T = K Q^T: D[m=t][n=q]; K-frags as A shared across both q-blocks
    f32x4 st[4][2];
#pragma unroll
    for (int tb = 0; tb < 4; tb++) {
      bf16x8 ak0 = *(const bf16x8*)&Ks[(tb * 16 + l16) * KST + quad * 8];
      bf16x8 ak1 = *(const bf16x8*)&Ks[(tb * 16 + l16) * KST + 32 + quad * 8];
#pragma unroll
      for (int qi = 0; qi < 2; qi++) {
        f32x4 s = (f32x4){0.f, 0.f, 0.f, 0.f};
        s = __builtin_amdgcn_mfma_f32_16x16x32_bf16(ak0, bq[qi][0], s, 0, 0, 0);
        s = __builtin_amdgcn_mfma_f32_16x16x32_bf16(ak1, bq[qi][1], s, 0, 0, 0);
        st[tb][qi] = s;
      }
    }

    // mask + exp2 + packed b64 store of P[q][t] (per-wave region, no barrier needed)
#pragma unroll
    for (int qi = 0; qi < 2; qi++) {
      int qlow = qrow0 + qi * 16;          // this block's q = qlow + l16
      if (j * 64 + 63 > qlow) {            // near-diagonal tiles only
        int qg = qlow + l16;
#pragma unroll
        for (int tb = 0; tb < 4; tb++) {
          int tg = j * 64 + tb * 16 + quad * 4;
#pragma unroll
          for (int i = 0; i < 4; i++) {
            if (tg + i > qg) st[tb][qi][i] = -__builtin_inff();
          }
        }
      }
#pragma unroll
      for (int tb = 0; tb < 4; tb++) {
        ushort4 w;
        w.x = bftrunc(__builtin_amdgcn_exp2f(st[tb][qi][0]));
        w.y = bftrunc(__builtin_amdgcn_exp2f(st[tb][qi][1]));
        w.z = bftrunc(__builtin_amdgcn_exp2f(st[tb][qi][2]));
        w.w = bftrunc(__builtin_amdgcn_exp2f(st[tb][qi][3]));
        *(ushort4*)&Pw[(qi * 16 + l16) * PST + tb * 16 + quad * 4] = w;
      }
    }

    bf16x8 ap[2][2];
#pragma unroll
    for (int qi = 0; qi < 2; qi++) {
      ap[qi][0] = *(const bf16x8*)&Pw[(qi * 16 + l16) * PST + quad * 8];
      ap[qi][1] = *(const bf16x8*)&Pw[(qi * 16 + l16) * PST + 32 + quad * 8];
      lacc[qi] = __builtin_amdgcn_mfma_f32_16x16x32_bf16(ap[qi][0], vones, lacc[qi], 0, 0, 0);
      lacc[qi] = __builtin_amdgcn_mfma_f32_16x16x32_bf16(ap[qi][1], vones, lacc[qi], 0, 0, 0);
    }
#pragma unroll
    for (int d = 0; d < 4; d++) {
      bf16x8 bv0 = *(const bf16x8*)&Vs[(d * 16 + l16) * KST + quad * 8];
      bf16x8 bv1 = *(const bf16x8*)&Vs[(d * 16 + l16) * KST + 32 + quad * 8];
#pragma unroll
      for (int qi = 0; qi < 2; qi++) {
        oacc[qi][d] = __builtin_amdgcn_mfma_f32_16x16x32_bf16(ap[qi][0], bv0, oacc[qi][d], 0, 0, 0);
        oacc[qi][d] = __builtin_amdgcn_mfma_f32_16x16x32_bf16(ap[qi][1], bv1, oacc[qi][d], 0, 0, 0);
      }
    }
  }

#pragma unroll
  for (int qi = 0; qi < 2; qi++) {
#pragma unroll
    for (int i = 0; i < 4; i++) {
      int tq = qrow0 + qi * 16 + quad * 4 + i;
      float inv = 1.f / lacc[qi][i];
#pragma unroll
      for (int d = 0; d < 4; d++) {
        y[((size_t)(b * T_SZ) + tq) * C_SZ + h * HD + d * 16 + l16] = f2bf(oacc[qi][d][i] * inv);
      }
    }
  }
}

extern "C" void kernel_launch(void* const* d_in, const int* in_sizes, int n_in,
                              void* d_out, int out_size, void* d_ws, size_t ws_size,
                              hipStream_t stream) {
  const float* x    = (const float*)d_in[0];
  const float* ve   = (const float*)d_in[1];
  const float* cosb = (const float*)d_in[2];
  const float* sinb = (const float*)d_in[3];
  const float* Wq   = (const float*)d_in[4];
  const float* Wk   = (const float*)d_in[5];
  const float* Wv   = (const float*)d_in[6];
  const float* Wo   = (const float*)d_in[7];
  const float* Wg   = (const float*)d_in[8];
  float* out = (float*)d_out;

  const size_t MB = 1024 * 1024;
  char* ws = (char*)d_ws;
  unsigned short* xb    = (unsigned short*)(ws);             // 8 MB (reused as yb)
  unsigned short* wqkvb = (unsigned short*)(ws + 8 * MB);    // 3 MB
  unsigned short* wob   = (unsigned short*)(ws + 11 * MB);   // 2 MB
  unsigned short* qab   = (unsigned short*)(ws + 13 * MB);   // 8 MB
  unsigned short* kab   = (unsigned short*)(ws + 21 * MB);   // 2 MB
  unsigned short* vtb   = (unsigned short*)(ws + 23 * MB);   // 2 MB
  float*          gateA = (float*)(ws + 25 * MB);            // 64 KB
  unsigned short* yb    = xb;                                // reuse after gemm_qkv

  CvtArgs ca;
  ca.s0 = x;  ca.d0 = xb;
  ca.s1 = Wq; ca.d1 = wqkvb;
  ca.s2 = Wk; ca.d2 = wqkvb + 1024 * 1024;
  ca.s3 = Wv; ca.d3 = wqkvb + 1280 * 1024;
  ca.s4 = Wo; ca.d4 = wob;
  ca.x = x; ca.Wg = Wg; ca.gate = gateA;
  cvt_all<<<6720, 256, 0, stream>>>(ca);

  gemm_qkv<<<dim3(QKV_N / 128, (B_SZ * T_SZ) / 64), 256, 0, stream>>>(
      xb, wqkvb, ve, cosb, sinb, gateA, qab, kab, vtb);

  attn<<<512, 256, 0, stream>>>(qab, kab, vtb, yb);

  gemm_bt<<<dim3(C_SZ / 128, (B_SZ * T_SZ) / 64), 256, 0, stream>>>(
      yb, wob, out, C_SZ, C_SZ);
}